// Round 3
// baseline (151.998 us; speedup 1.0000x reference)
//
#include <hip/hip_runtime.h>

typedef unsigned int uint;
typedef unsigned short ushort;
typedef __attribute__((ext_vector_type(8))) short short8;
typedef __attribute__((ext_vector_type(4))) float f32x4;

#define B_   512
#define V_   256
#define M_   128
#define H_   512
#define T_   16
#define KTOT 34816   // V_*M_ + M_*T_

// ---------------- helpers ----------------
__device__ __forceinline__ ushort f2bf(float f) {
  uint u = __builtin_bit_cast(uint, f);
  u += 0x7fffu + ((u >> 16) & 1u);   // RNE
  return (ushort)(u >> 16);
}

// ---------------- kernel 1: per-batch prep ----------------
__global__ __launch_bounds__(256) void prep_kernel(
    const float* __restrict__ x, const float* __restrict__ mem,
    const int* __restrict__ timings, const float* __restrict__ msurp,
    const float* __restrict__ b1,
    ushort* __restrict__ A, float* __restrict__ h_pre)
{
  const int b = blockIdx.x, tid = threadIdx.x;
  __shared__ int s_t[M_];
  __shared__ int s_row[M_];
  __shared__ int s_st[M_];
  __shared__ int s_idx;

  if (tid < 64) {
    float v0 = msurp[b * M_ + tid];
    float v1 = msurp[b * M_ + tid + 64];
    float v; int i;
    if (v1 < v0) { v = v1; i = tid + 64; } else { v = v0; i = tid; }
    #pragma unroll
    for (int off = 32; off > 0; off >>= 1) {
      float ov = __shfl_down(v, off);
      int   oi = __shfl_down(i, off);
      if (ov < v || (ov == v && oi < i)) { v = ov; i = oi; }
    }
    if (tid == 0) s_idx = i;
  }
  __syncthreads();
  const int idx = s_idx;

  if (tid < M_) {
    int t = timings[b * M_ + tid] + 1;
    if (tid == idx) t = 0;
    s_t[tid] = t;
  }
  h_pre[(size_t)b * H_ + tid]       = b1[tid];
  h_pre[(size_t)b * H_ + 256 + tid] = b1[256 + tid];
  __syncthreads();

  if (tid < M_) {
    const int t = s_t[tid];
    int r = 0;
    for (int j = 0; j < M_; ++j) {
      int tj = s_t[j];
      r += (tj < t || (tj == t && j < tid)) ? 1 : 0;
    }
    s_row[r] = tid;   // order[r] = tid
    s_st[r]  = t;     // sorted_t[r]
  }
  __syncthreads();

  // bits region
  if (tid < M_) {
    const int t = s_st[tid];
    uint p[8];
    #pragma unroll
    for (int h = 0; h < 8; ++h) {
      uint lo = ((t >> (2 * h)) & 1) ? 0x3F80u : 0u;
      uint hi = ((t >> (2 * h + 1)) & 1) ? 0x3F80u : 0u;
      p[h] = lo | (hi << 16);
    }
    uint4* dst = (uint4*)(A + (size_t)b * KTOT + V_ * M_ + tid * T_);
    uint4 w0; w0.x = p[0]; w0.y = p[1]; w0.z = p[2]; w0.w = p[3];
    uint4 w1; w1.x = p[4]; w1.y = p[5]; w1.z = p[6]; w1.w = p[7];
    dst[0] = w0; dst[1] = w1;
  }

  // gather rows
  const int lane = tid & 63, sub = tid >> 6;
  for (int it = 0; it < 32; ++it) {
    const int slot = it * 4 + sub;
    const int rowm = s_row[slot];
    const float* src = (rowm == idx) ? (x + (size_t)b * V_)
                                     : (mem + ((size_t)b * M_ + rowm) * V_);
    f32x4 v = *(const f32x4*)(src + lane * 4);
    uint2 o;
    o.x = (uint)f2bf(v[0]) | ((uint)f2bf(v[1]) << 16);
    o.y = (uint)f2bf(v[2]) | ((uint)f2bf(v[3]) << 16);
    *(uint2*)(A + (size_t)b * KTOT + slot * V_ + lane * 4) = o;
  }
}

// ---------------- kernel 2: LDS-tiled transpose  W1[K][512] f32 -> W1T[512][K] bf16
__global__ __launch_bounds__(256) void transpose_w1_kernel(
    const float* __restrict__ W1, ushort* __restrict__ W1T)
{
  __shared__ float tile[64][68];
  const int kt = blockIdx.x * 64;
  const int nt = blockIdx.y * 64;
  const int tid = threadIdx.x;

  {
    const int rn4 = (tid & 15) * 4;
    const int rk  = tid >> 4;
    #pragma unroll
    for (int p = 0; p < 4; ++p) {
      const int k = rk + p * 16;
      f32x4 v = *(const f32x4*)(W1 + (size_t)(kt + k) * H_ + nt + rn4);
      *(f32x4*)&tile[k][rn4] = v;
    }
  }
  __syncthreads();

  {
    const int wn = tid >> 2;
    const int wk = (tid & 3) * 16;
    uint w[8];
    #pragma unroll
    for (int c = 0; c < 8; ++c) {
      float lo = tile[wk + 2 * c][wn];
      float hi = tile[wk + 2 * c + 1][wn];
      w[c] = (uint)f2bf(lo) | ((uint)f2bf(hi) << 16);
    }
    uint4* dst = (uint4*)(W1T + (size_t)(nt + wn) * KTOT + kt + wk);
    uint4 o0; o0.x = w[0]; o0.y = w[1]; o0.z = w[2]; o0.w = w[3];
    uint4 o1; o1.x = w[4]; o1.y = w[5]; o1.z = w[6]; o1.w = w[7];
    dst[0] = o0; dst[1] = o1;
  }
}

// ---------------- kernel 3: split-K bf16 MFMA GEMM ----------------
// SPLITK=68 -> KCH=512, NCHU=16; grid = 8 tiles * 68 = 544 blocks (>=2/CU)
#define BM 256
#define BN 128
#define SPLITK 68
#define KCH 512
#define NCHU 16

#define GLD16(g, l) __builtin_amdgcn_global_load_lds( \
  (const __attribute__((address_space(1))) void*)(g), \
  (__attribute__((address_space(3))) void*)(l), 16, 0, 0)

__global__ __launch_bounds__(512) void gemm1_kernel(
    const ushort* __restrict__ A, const ushort* __restrict__ Bt,
    float* __restrict__ h_pre)
{
  __shared__ __align__(16) ushort As[2][BM * 32];
  __shared__ __align__(16) ushort Bs[2][BN * 32];

  const int bid  = blockIdx.x;
  const int tile = bid & 7;      // 2 m-tiles x 4 n-tiles
  const int sk   = bid >> 3;     // 0..67
  const int b0   = (tile >> 2) * BM;
  const int n0   = (tile & 3) * BN;
  const int tid  = threadIdx.x, wave = tid >> 6, lane = tid & 63;
  const int wm   = wave >> 1;
  const int wn   = wave & 1;
  const long kb0 = (long)sk * KCH;

  f32x4 acc[4][4];
  #pragma unroll
  for (int i = 0; i < 4; ++i)
    #pragma unroll
    for (int j = 0; j < 4; ++j) acc[i][j] = (f32x4)0.f;

  const int ar  = wave * 32 + (lane >> 2);
  const int bn  = wave * 16 + (lane >> 2);
  const int akk = (lane & 3) * 8;

  auto stage = [&](int buf, long kb) {
    GLD16(A  + ((size_t)(b0 + ar))      * KTOT + kb + akk, &As[buf][(wave * 32) * 32]);
    GLD16(A  + ((size_t)(b0 + ar + 16)) * KTOT + kb + akk, &As[buf][(wave * 32 + 16) * 32]);
    GLD16(Bt + ((size_t)(n0 + bn))      * KTOT + kb + akk, &Bs[buf][(wave * 16) * 32]);
  };

  stage(0, kb0);
  int cur = 0;
  for (int c = 0; c < NCHU; ++c) {
    __syncthreads();
    if (c + 1 < NCHU) stage(cur ^ 1, kb0 + (long)(c + 1) * 32);
    const ushort* as = &As[cur][(wm * 64 + (lane & 15)) * 32 + (lane >> 4) * 8];
    const ushort* bs = &Bs[cur][(wn * 64 + (lane & 15)) * 32 + (lane >> 4) * 8];
    short8 af[4], bf[4];
    #pragma unroll
    for (int i = 0; i < 4; ++i) {
      af[i] = *(const short8*)(as + i * 16 * 32);
      bf[i] = *(const short8*)(bs + i * 16 * 32);
    }
    #pragma unroll
    for (int i = 0; i < 4; ++i)
      #pragma unroll
      for (int j = 0; j < 4; ++j)
        acc[i][j] = __builtin_amdgcn_mfma_f32_16x16x32_bf16(af[i], bf[j], acc[i][j], 0, 0, 0);
    cur ^= 1;
  }

  const int row0 = b0 + wm * 64 + (lane >> 4) * 4;
  const int col0 = n0 + wn * 64 + (lane & 15);
  #pragma unroll
  for (int i = 0; i < 4; ++i)
    #pragma unroll
    for (int j = 0; j < 4; ++j)
      #pragma unroll
      for (int r = 0; r < 4; ++r)
        atomicAdd(&h_pre[(size_t)(row0 + i * 16 + r) * H_ + col0 + j * 16], acc[i][j][r]);
}

// ---------------- kernel 4: out = relu(h_pre) @ W2 + b2 (fp32) ----------------
__global__ __launch_bounds__(256) void gemm2_kernel(
    const float* __restrict__ h_pre, const float* __restrict__ W2,
    const float* __restrict__ b2, float* __restrict__ out)
{
  const int bb = blockIdx.x * 4;
  const int v  = threadIdx.x;
  __shared__ float hs[4][H_];
  #pragma unroll
  for (int i = 0; i < 8; ++i) {
    int id = i * 256 + v;
    hs[id >> 9][id & 511] =
        fmaxf(h_pre[(size_t)(bb + (id >> 9)) * H_ + (id & 511)], 0.f);
  }
  __syncthreads();
  float a0 = 0.f, a1 = 0.f, a2 = 0.f, a3 = 0.f;
  for (int j4 = 0; j4 < H_ / 4; ++j4) {
    f32x4 h0 = *(const f32x4*)&hs[0][j4 * 4];
    f32x4 h1 = *(const f32x4*)&hs[1][j4 * 4];
    f32x4 h2 = *(const f32x4*)&hs[2][j4 * 4];
    f32x4 h3 = *(const f32x4*)&hs[3][j4 * 4];
    #pragma unroll
    for (int t = 0; t < 4; ++t) {
      float w = W2[(size_t)(j4 * 4 + t) * V_ + v];
      a0 += h0[t] * w; a1 += h1[t] * w; a2 += h2[t] * w; a3 += h3[t] * w;
    }
  }
  const float bias = b2[v];
  out[(size_t)(bb + 0) * V_ + v] = a0 + bias;
  out[(size_t)(bb + 1) * V_ + v] = a1 + bias;
  out[(size_t)(bb + 2) * V_ + v] = a2 + bias;
  out[(size_t)(bb + 3) * V_ + v] = a3 + bias;
}

// ---------------- launch ----------------
extern "C" void kernel_launch(void* const* d_in, const int* in_sizes, int n_in,
                              void* d_out, int out_size, void* d_ws, size_t ws_size,
                              hipStream_t stream) {
  const float* x   = (const float*)d_in[0];
  const float* mem = (const float*)d_in[1];
  const int*   tim = (const int*)d_in[2];
  const float* msu = (const float*)d_in[3];
  const float* W1  = (const float*)d_in[5];
  const float* b1  = (const float*)d_in[6];
  const float* W2  = (const float*)d_in[7];
  const float* b2  = (const float*)d_in[8];
  float* out = (float*)d_out;

  char* ws = (char*)d_ws;
  const size_t abytes = (size_t)B_ * KTOT * 2;
  ushort* A_ws  = (ushort*)ws;
  ushort* W1T   = (ushort*)(ws + abytes);
  float*  h_pre = (float*)(ws + 2 * abytes);

  prep_kernel<<<B_, 256, 0, stream>>>(x, mem, tim, msu, b1, A_ws, h_pre);
  transpose_w1_kernel<<<dim3(KTOT / 64, H_ / 64), 256, 0, stream>>>(W1, W1T);
  gemm1_kernel<<<8 * SPLITK, 512, 0, stream>>>(A_ws, W1T, h_pre);
  gemm2_kernel<<<B_ / 4, 256, 0, stream>>>(h_pre, W2, b2, out);
}

// Round 4
// 111.214 us; speedup vs baseline: 1.3667x; 1.3667x over previous
//
#include <hip/hip_runtime.h>

typedef unsigned int uint;
typedef unsigned short ushort;
typedef __attribute__((ext_vector_type(8))) short short8;
typedef __attribute__((ext_vector_type(4))) float f32x4;

#define B_   512
#define V_   256
#define M_   128
#define H_   512
#define T_   16
#define KTOT 34816   // V_*M_ + M_*T_

// ---------------- helpers ----------------
__device__ __forceinline__ ushort f2bf(float f) {
  uint u = __builtin_bit_cast(uint, f);
  u += 0x7fffu + ((u >> 16) & 1u);   // RNE
  return (ushort)(u >> 16);
}

// sigma-swizzle: within each 32-element (64B) k-group, XOR the 16B-chunk index
// (bits 3-4 of element offset) with ((row>>1)&3). Writers apply it; gemm1's
// global_load_lds copies whole 64B groups verbatim; frag reads XOR it back.
__device__ __forceinline__ int swz_k(int k, int row) {
  return (k & ~31) | (((((k >> 3) & 3) ^ ((row >> 1) & 3)) << 3)) | (k & 7);
}

// ---------------- kernel 1: per-batch prep ----------------
__global__ __launch_bounds__(256) void prep_kernel(
    const float* __restrict__ x, const float* __restrict__ mem,
    const int* __restrict__ timings, const float* __restrict__ msurp,
    const float* __restrict__ b1,
    ushort* __restrict__ A, float* __restrict__ h_pre)
{
  const int b = blockIdx.x, tid = threadIdx.x;
  __shared__ int s_t[M_];
  __shared__ int s_row[M_];
  __shared__ int s_st[M_];
  __shared__ int s_idx;

  if (tid < 64) {
    float v0 = msurp[b * M_ + tid];
    float v1 = msurp[b * M_ + tid + 64];
    float v; int i;
    if (v1 < v0) { v = v1; i = tid + 64; } else { v = v0; i = tid; }
    #pragma unroll
    for (int off = 32; off > 0; off >>= 1) {
      float ov = __shfl_down(v, off);
      int   oi = __shfl_down(i, off);
      if (ov < v || (ov == v && oi < i)) { v = ov; i = oi; }
    }
    if (tid == 0) s_idx = i;
  }
  __syncthreads();
  const int idx = s_idx;

  if (tid < M_) {
    int t = timings[b * M_ + tid] + 1;
    if (tid == idx) t = 0;
    s_t[tid] = t;
  }
  // h_pre init = b1 (used by atomic fallback; overwritten by reduce otherwise)
  h_pre[(size_t)b * H_ + tid]       = b1[tid];
  h_pre[(size_t)b * H_ + 256 + tid] = b1[256 + tid];
  __syncthreads();

  if (tid < M_) {
    const int t = s_t[tid];
    int r = 0;
    for (int j = 0; j < M_; ++j) {
      int tj = s_t[j];
      r += (tj < t || (tj == t && j < tid)) ? 1 : 0;
    }
    s_row[r] = tid;   // order[r] = tid
    s_st[r]  = t;     // sorted_t[r]
  }
  __syncthreads();

  // bits region (k >= 32768), swizzled writes
  if (tid < M_) {
    const int t = s_st[tid];
    uint p[8];
    #pragma unroll
    for (int h = 0; h < 8; ++h) {
      uint lo = ((t >> (2 * h)) & 1) ? 0x3F80u : 0u;
      uint hi = ((t >> (2 * h + 1)) & 1) ? 0x3F80u : 0u;
      p[h] = lo | (hi << 16);
    }
    const int k0 = V_ * M_ + tid * T_;
    uint4 w0; w0.x = p[0]; w0.y = p[1]; w0.z = p[2]; w0.w = p[3];
    uint4 w1; w1.x = p[4]; w1.y = p[5]; w1.z = p[6]; w1.w = p[7];
    *(uint4*)(A + (size_t)b * KTOT + swz_k(k0, b))     = w0;
    *(uint4*)(A + (size_t)b * KTOT + swz_k(k0 + 8, b)) = w1;
  }

  // gather rows, swizzled writes (8B pieces stay within one 16B chunk)
  const int lane = tid & 63, sub = tid >> 6;
  for (int it = 0; it < 32; ++it) {
    const int slot = it * 4 + sub;
    const int rowm = s_row[slot];
    const float* src = (rowm == idx) ? (x + (size_t)b * V_)
                                     : (mem + ((size_t)b * M_ + rowm) * V_);
    f32x4 v = *(const f32x4*)(src + lane * 4);
    uint2 o;
    o.x = (uint)f2bf(v[0]) | ((uint)f2bf(v[1]) << 16);
    o.y = (uint)f2bf(v[2]) | ((uint)f2bf(v[3]) << 16);
    const int k = slot * V_ + lane * 4;
    *(uint2*)(A + (size_t)b * KTOT + swz_k(k, b)) = o;
  }
}

// ---------------- kernel 2: LDS-tiled transpose  W1[K][512] f32 -> W1T[512][K] bf16 (swizzled)
__global__ __launch_bounds__(256) void transpose_w1_kernel(
    const float* __restrict__ W1, ushort* __restrict__ W1T)
{
  __shared__ float tile[64][68];
  const int kt = blockIdx.x * 64;
  const int nt = blockIdx.y * 64;
  const int tid = threadIdx.x;

  {
    const int rn4 = (tid & 15) * 4;
    const int rk  = tid >> 4;
    #pragma unroll
    for (int p = 0; p < 4; ++p) {
      const int k = rk + p * 16;
      f32x4 v = *(const f32x4*)(W1 + (size_t)(kt + k) * H_ + nt + rn4);
      *(f32x4*)&tile[k][rn4] = v;
    }
  }
  __syncthreads();

  {
    const int wn = tid >> 2;         // row n within tile
    const int wk = (tid & 3) * 16;
    const int n  = nt + wn;
    uint w[8];
    #pragma unroll
    for (int c = 0; c < 8; ++c) {
      float lo = tile[wk + 2 * c][wn];
      float hi = tile[wk + 2 * c + 1][wn];
      w[c] = (uint)f2bf(lo) | ((uint)f2bf(hi) << 16);
    }
    uint4 o0; o0.x = w[0]; o0.y = w[1]; o0.z = w[2]; o0.w = w[3];
    uint4 o1; o1.x = w[4]; o1.y = w[5]; o1.z = w[6]; o1.w = w[7];
    const int kg = kt + wk;
    *(uint4*)(W1T + (size_t)n * KTOT + swz_k(kg, n))     = o0;
    *(uint4*)(W1T + (size_t)n * KTOT + swz_k(kg + 8, n)) = o1;
  }
}

// ---------------- kernel 3: split-K bf16 MFMA GEMM ----------------
// 3-buffer LDS, 1 barrier/iter, counted vmcnt(3): loads never drain.
#define BM 256
#define BN 128
#define SPLITK 32
#define KCH 1088
#define NCHU 34
#define NBUF 3

#define GLD16(g, l) __builtin_amdgcn_global_load_lds( \
  (const __attribute__((address_space(1))) void*)(g), \
  (__attribute__((address_space(3))) void*)(l), 16, 0, 0)

template<bool USE_ATOMIC>
__global__ __launch_bounds__(512) void gemm1_kernel(
    const ushort* __restrict__ A, const ushort* __restrict__ Bt,
    float* __restrict__ dst)   // h_pre (atomic) or partials P[SPLITK][512][512]
{
  __shared__ __align__(16) ushort As[NBUF][BM * 32];   // 48 KB
  __shared__ __align__(16) ushort Bs[NBUF][BN * 32];   // 24 KB

  const int bid  = blockIdx.x;
  const int tile = bid & 7;      // 2 m-tiles x 4 n-tiles
  const int sk   = bid >> 3;     // 0..31
  const int b0   = (tile >> 2) * BM;
  const int n0   = (tile & 3) * BN;
  const int tid  = threadIdx.x, wave = tid >> 6, lane = tid & 63;
  const int wm   = wave >> 1;
  const int wn   = wave & 1;
  const long kb0 = (long)sk * KCH;

  f32x4 acc[4][4];
  #pragma unroll
  for (int i = 0; i < 4; ++i)
    #pragma unroll
    for (int j = 0; j < 4; ++j) acc[i][j] = (f32x4)0.f;

  const int ar  = wave * 32 + (lane >> 2);
  const int bn  = wave * 16 + (lane >> 2);
  const int akk = (lane & 3) * 8;

  auto stage = [&](int buf, long kb) {
    GLD16(A  + ((size_t)(b0 + ar))      * KTOT + kb + akk, &As[buf][(wave * 32) * 32]);
    GLD16(A  + ((size_t)(b0 + ar + 16)) * KTOT + kb + akk, &As[buf][(wave * 32 + 16) * 32]);
    GLD16(Bt + ((size_t)(n0 + bn))      * KTOT + kb + akk, &Bs[buf][(wave * 16) * 32]);
  };

  // de-swizzle read offset: logical chunk (lane>>4) stored at chunk^sigma(row),
  // sigma(row) = (row>>1)&3 = (lane>>1)&3 here (frag rows offset by multiples of 16)
  const int xo = (((lane >> 4) ^ ((lane >> 1) & 3)) * 8);

  stage(0, kb0);
  stage(1, kb0 + 32);
  for (int c = 0; c < NCHU; ++c) {
    if (c < NCHU - 1) asm volatile("s_waitcnt vmcnt(3)" ::: "memory");
    else              asm volatile("s_waitcnt vmcnt(0)" ::: "memory");
    __builtin_amdgcn_s_barrier();
    __builtin_amdgcn_sched_barrier(0);
    if (c + 2 < NCHU) stage((c + 2) % NBUF, kb0 + (long)(c + 2) * 32);
    const int cur = c % NBUF;
    const ushort* as = &As[cur][(wm * 64 + (lane & 15)) * 32 + xo];
    const ushort* bs = &Bs[cur][(wn * 64 + (lane & 15)) * 32 + xo];
    short8 af[4], bf[4];
    #pragma unroll
    for (int i = 0; i < 4; ++i) {
      af[i] = *(const short8*)(as + i * 16 * 32);
      bf[i] = *(const short8*)(bs + i * 16 * 32);
    }
    #pragma unroll
    for (int i = 0; i < 4; ++i)
      #pragma unroll
      for (int j = 0; j < 4; ++j)
        acc[i][j] = __builtin_amdgcn_mfma_f32_16x16x32_bf16(af[i], bf[j], acc[i][j], 0, 0, 0);
  }

  const int row0 = b0 + wm * 64 + (lane >> 4) * 4;
  const int col0 = n0 + wn * 64 + (lane & 15);
  if constexpr (USE_ATOMIC) {
    #pragma unroll
    for (int i = 0; i < 4; ++i)
      #pragma unroll
      for (int j = 0; j < 4; ++j)
        #pragma unroll
        for (int r = 0; r < 4; ++r)
          atomicAdd(&dst[(size_t)(row0 + i * 16 + r) * H_ + col0 + j * 16], acc[i][j][r]);
  } else {
    float* P = dst + (size_t)sk * (B_ * H_);
    #pragma unroll
    for (int i = 0; i < 4; ++i)
      #pragma unroll
      for (int j = 0; j < 4; ++j)
        #pragma unroll
        for (int r = 0; r < 4; ++r)
          P[(size_t)(row0 + i * 16 + r) * H_ + col0 + j * 16] = acc[i][j][r];
  }
}

// ---------------- kernel 3b: reduce partials: h = b1 + sum_sk P[sk] ----------------
__global__ __launch_bounds__(256) void reduce_kernel(
    const float* __restrict__ P, const float* __restrict__ b1,
    float* __restrict__ h_pre)
{
  const int gid = blockIdx.x * 256 + threadIdx.x;   // 65536 threads, f32x4 each
  const int e   = gid * 4;
  f32x4 s = *(const f32x4*)(b1 + (e & (H_ - 1)));
  #pragma unroll 4
  for (int sk = 0; sk < SPLITK; ++sk)
    s += *(const f32x4*)(P + (size_t)sk * (B_ * H_) + e);
  *(f32x4*)(h_pre + e) = s;
}

// ---------------- kernel 4: out = relu(h_pre) @ W2 + b2 (fp32) ----------------
__global__ __launch_bounds__(256) void gemm2_kernel(
    const float* __restrict__ h_pre, const float* __restrict__ W2,
    const float* __restrict__ b2, float* __restrict__ out)
{
  const int bb = blockIdx.x * 4;
  const int v  = threadIdx.x;
  __shared__ float hs[4][H_];
  #pragma unroll
  for (int i = 0; i < 8; ++i) {
    int id = i * 256 + v;
    hs[id >> 9][id & 511] =
        fmaxf(h_pre[(size_t)(bb + (id >> 9)) * H_ + (id & 511)], 0.f);
  }
  __syncthreads();
  float a0 = 0.f, a1 = 0.f, a2 = 0.f, a3 = 0.f;
  for (int j4 = 0; j4 < H_ / 4; ++j4) {
    f32x4 h0 = *(const f32x4*)&hs[0][j4 * 4];
    f32x4 h1 = *(const f32x4*)&hs[1][j4 * 4];
    f32x4 h2 = *(const f32x4*)&hs[2][j4 * 4];
    f32x4 h3 = *(const f32x4*)&hs[3][j4 * 4];
    #pragma unroll
    for (int t = 0; t < 4; ++t) {
      float w = W2[(size_t)(j4 * 4 + t) * V_ + v];
      a0 += h0[t] * w; a1 += h1[t] * w; a2 += h2[t] * w; a3 += h3[t] * w;
    }
  }
  const float bias = b2[v];
  out[(size_t)(bb + 0) * V_ + v] = a0 + bias;
  out[(size_t)(bb + 1) * V_ + v] = a1 + bias;
  out[(size_t)(bb + 2) * V_ + v] = a2 + bias;
  out[(size_t)(bb + 3) * V_ + v] = a3 + bias;
}

// ---------------- launch ----------------
extern "C" void kernel_launch(void* const* d_in, const int* in_sizes, int n_in,
                              void* d_out, int out_size, void* d_ws, size_t ws_size,
                              hipStream_t stream) {
  const float* x   = (const float*)d_in[0];
  const float* mem = (const float*)d_in[1];
  const int*   tim = (const int*)d_in[2];
  const float* msu = (const float*)d_in[3];
  const float* W1  = (const float*)d_in[5];
  const float* b1  = (const float*)d_in[6];
  const float* W2  = (const float*)d_in[7];
  const float* b2  = (const float*)d_in[8];
  float* out = (float*)d_out;

  char* ws = (char*)d_ws;
  const size_t abytes = (size_t)B_ * KTOT * 2;          // 35,651,584
  const size_t pbytes = (size_t)SPLITK * B_ * H_ * 4;   // 33,554,432
  const size_t hbytes = (size_t)B_ * H_ * 4;            // 1,048,576
  const bool partials = ws_size >= 2 * abytes + pbytes + hbytes;

  ushort* A_ws = (ushort*)ws;
  ushort* W1T  = (ushort*)(ws + abytes);
  float*  P    = (float*)(ws + 2 * abytes);
  float*  h_pre = partials ? (float*)(ws + 2 * abytes + pbytes)
                           : (float*)(ws + 2 * abytes);

  prep_kernel<<<B_, 256, 0, stream>>>(x, mem, tim, msu, b1, A_ws, h_pre);
  transpose_w1_kernel<<<dim3(KTOT / 64, H_ / 64), 256, 0, stream>>>(W1, W1T);
  if (partials) {
    gemm1_kernel<false><<<8 * SPLITK, 512, 0, stream>>>(A_ws, W1T, P);
    reduce_kernel<<<(B_ * H_ / 4) / 256, 256, 0, stream>>>(P, b1, h_pre);
  } else {
    gemm1_kernel<true><<<8 * SPLITK, 512, 0, stream>>>(A_ws, W1T, h_pre);
  }
  gemm2_kernel<<<B_ / 4, 256, 0, stream>>>(h_pre, W2, b2, out);
}

// Round 5
// 91.903 us; speedup vs baseline: 1.6539x; 1.2101x over previous
//
#include <hip/hip_runtime.h>

typedef unsigned int uint;
typedef unsigned short ushort;
typedef __attribute__((ext_vector_type(8))) short short8;
typedef __attribute__((ext_vector_type(4))) float f32x4;

#define B_   512
#define V_   256
#define M_   128
#define H_   512
#define T_   16
#define KTOT 34816   // V_*M_ + M_*T_

// ---------------- helpers ----------------
__device__ __forceinline__ ushort f2bf(float f) {
  uint u = __builtin_bit_cast(uint, f);
  u += 0x7fffu + ((u >> 16) & 1u);   // RNE
  return (ushort)(u >> 16);
}

// sigma-swizzle: within each 32-element (64B) k-group, XOR the 16B-chunk index
// with ((row>>1)&3). A's writer (prep) applies it; gemm1 reads it back.
__device__ __forceinline__ int swz_k(int k, int row) {
  return (k & ~31) | (((((k >> 3) & 3) ^ ((row >> 1) & 3)) << 3)) | (k & 7);
}

// ---------------- kernel 1: per-batch prep ----------------
__global__ __launch_bounds__(256) void prep_kernel(
    const float* __restrict__ x, const float* __restrict__ mem,
    const int* __restrict__ timings, const float* __restrict__ msurp,
    const float* __restrict__ b1,
    ushort* __restrict__ A, float* __restrict__ h_pre)
{
  const int b = blockIdx.x, tid = threadIdx.x;
  __shared__ int s_t[M_];
  __shared__ int s_row[M_];
  __shared__ int s_st[M_];
  __shared__ int s_idx;

  if (tid < 64) {
    float v0 = msurp[b * M_ + tid];
    float v1 = msurp[b * M_ + tid + 64];
    float v; int i;
    if (v1 < v0) { v = v1; i = tid + 64; } else { v = v0; i = tid; }
    #pragma unroll
    for (int off = 32; off > 0; off >>= 1) {
      float ov = __shfl_down(v, off);
      int   oi = __shfl_down(i, off);
      if (ov < v || (ov == v && oi < i)) { v = ov; i = oi; }
    }
    if (tid == 0) s_idx = i;
  }
  __syncthreads();
  const int idx = s_idx;

  if (tid < M_) {
    int t = timings[b * M_ + tid] + 1;
    if (tid == idx) t = 0;
    s_t[tid] = t;
  }
  // h_pre init = b1 (consumed only by the atomic fallback path)
  h_pre[(size_t)b * H_ + tid]       = b1[tid];
  h_pre[(size_t)b * H_ + 256 + tid] = b1[256 + tid];
  __syncthreads();

  if (tid < M_) {
    const int t = s_t[tid];
    int r = 0;
    for (int j = 0; j < M_; ++j) {
      int tj = s_t[j];
      r += (tj < t || (tj == t && j < tid)) ? 1 : 0;
    }
    s_row[r] = tid;   // order[r] = tid
    s_st[r]  = t;     // sorted_t[r]
  }
  __syncthreads();

  // bits region (k >= 32768), swizzled writes
  if (tid < M_) {
    const int t = s_st[tid];
    uint p[8];
    #pragma unroll
    for (int h = 0; h < 8; ++h) {
      uint lo = ((t >> (2 * h)) & 1) ? 0x3F80u : 0u;
      uint hi = ((t >> (2 * h + 1)) & 1) ? 0x3F80u : 0u;
      p[h] = lo | (hi << 16);
    }
    const int k0 = V_ * M_ + tid * T_;
    uint4 w0; w0.x = p[0]; w0.y = p[1]; w0.z = p[2]; w0.w = p[3];
    uint4 w1; w1.x = p[4]; w1.y = p[5]; w1.z = p[6]; w1.w = p[7];
    *(uint4*)(A + (size_t)b * KTOT + swz_k(k0, b))     = w0;
    *(uint4*)(A + (size_t)b * KTOT + swz_k(k0 + 8, b)) = w1;
  }

  // gather rows, swizzled writes (8B pieces stay within one 16B chunk)
  const int lane = tid & 63, sub = tid >> 6;
  for (int it = 0; it < 32; ++it) {
    const int slot = it * 4 + sub;
    const int rowm = s_row[slot];
    const float* src = (rowm == idx) ? (x + (size_t)b * V_)
                                     : (mem + ((size_t)b * M_ + rowm) * V_);
    f32x4 v = *(const f32x4*)(src + lane * 4);
    uint2 o;
    o.x = (uint)f2bf(v[0]) | ((uint)f2bf(v[1]) << 16);
    o.y = (uint)f2bf(v[2]) | ((uint)f2bf(v[3]) << 16);
    const int k = slot * V_ + lane * 4;
    *(uint2*)(A + (size_t)b * KTOT + swz_k(k, b)) = o;
  }
}

// ---------------- kernel 2: split-K bf16 MFMA GEMM, B staged from raw f32 W1 ----------------
// A: global_load_lds from pre-swizzled A_ws.  B: reg-stage W1 f32 -> cvt bf16 -> swizzled ds_write.
#define BM 256
#define BN 128
#define SPLITK 32
#define KCH 1088
#define NCHU 34

#define GLD16(g, l) __builtin_amdgcn_global_load_lds( \
  (const __attribute__((address_space(1))) void*)(g), \
  (__attribute__((address_space(3))) void*)(l), 16, 0, 0)

template<bool USE_ATOMIC>
__global__ __launch_bounds__(512) void gemm1_kernel(
    const ushort* __restrict__ A, const float* __restrict__ W1,
    float* __restrict__ dst)   // h_pre (atomic) or partials P[SPLITK][512][512]
{
  __shared__ __align__(16) ushort As[2][BM * 32];   // 32 KB
  __shared__ __align__(16) ushort Bs[2][BN * 32];   // 16 KB

  const int bid  = blockIdx.x;
  const int tile = bid & 7;      // 2 m-tiles x 4 n-tiles
  const int sk   = bid >> 3;     // 0..31
  const int b0   = (tile >> 2) * BM;
  const int n0   = (tile & 3) * BN;
  const int tid  = threadIdx.x, wave = tid >> 6, lane = tid & 63;
  const int wm   = wave >> 1;
  const int wn   = wave & 1;
  const long kb0 = (long)sk * KCH;

  f32x4 acc[4][4];
  #pragma unroll
  for (int i = 0; i < 4; ++i)
    #pragma unroll
    for (int j = 0; j < 4; ++j) acc[i][j] = (f32x4)0.f;

  // A staging (global_load_lds, linear dest)
  const int ar  = wave * 32 + (lane >> 2);
  const int akk = (lane & 3) * 8;
  auto stageA = [&](int buf, long kb) {
    GLD16(A + ((size_t)(b0 + ar))      * KTOT + kb + akk, &As[buf][(wave * 32) * 32]);
    GLD16(A + ((size_t)(b0 + ar + 16)) * KTOT + kb + akk, &As[buf][(wave * 32 + 16) * 32]);
  };

  // B staging: thread -> column n = n0+(tid&127), k-chunk kc = tid>>7 (8 k's)
  const int bn_  = tid & 127;
  const int bkc  = tid >> 7;                 // 0..3
  const float* w1p = W1 + (size_t)(kb0 + bkc * 8) * H_ + n0 + bn_;
  // swizzled LDS dest for this thread's 16B chunk
  ushort* bdst0 = &Bs[0][bn_ * 32 + ((bkc ^ ((bn_ >> 1) & 3)) * 8)];
  ushort* bdst1 = &Bs[1][bn_ * 32 + ((bkc ^ ((bn_ >> 1) & 3)) * 8)];

  float br[8];
  auto loadB = [&](float* r, int c) {
    const float* p = w1p + (size_t)c * 32 * H_;
    #pragma unroll
    for (int i = 0; i < 8; ++i) r[i] = p[(size_t)i * H_];
  };
  auto writeB = [&](const float* r, ushort* d) {
    uint4 o;
    o.x = (uint)f2bf(r[0]) | ((uint)f2bf(r[1]) << 16);
    o.y = (uint)f2bf(r[2]) | ((uint)f2bf(r[3]) << 16);
    o.z = (uint)f2bf(r[4]) | ((uint)f2bf(r[5]) << 16);
    o.w = (uint)f2bf(r[6]) | ((uint)f2bf(r[7]) << 16);
    *(uint4*)d = o;
  };

  // de-swizzle read offset for frag loads
  const int xo = (((lane >> 4) ^ ((lane >> 1) & 3)) * 8);

  // prologue
  stageA(0, kb0);
  loadB(br, 0);
  writeB(br, bdst0);
  __syncthreads();

  for (int c = 0; c < NCHU; ++c) {
    const int cur = c & 1;
    float br2[8];
    if (c + 1 < NCHU) {
      loadB(br2, c + 1);                        // 8 dword loads in flight
      stageA(cur ^ 1, kb0 + (long)(c + 1) * 32);
    }
    const ushort* as = &As[cur][(wm * 64 + (lane & 15)) * 32 + xo];
    const ushort* bs = &Bs[cur][(wn * 64 + (lane & 15)) * 32 + xo];
    short8 af[4], bf[4];
    #pragma unroll
    for (int i = 0; i < 4; ++i) {
      af[i] = *(const short8*)(as + i * 16 * 32);
      bf[i] = *(const short8*)(bs + i * 16 * 32);
    }
    #pragma unroll
    for (int i = 0; i < 4; ++i)
      #pragma unroll
      for (int j = 0; j < 4; ++j)
        acc[i][j] = __builtin_amdgcn_mfma_f32_16x16x32_bf16(af[i], bf[j], acc[i][j], 0, 0, 0);
    if (c + 1 < NCHU)
      writeB(br2, cur ? bdst0 : bdst1);         // cvt waits the 8 dwords only
    __syncthreads();                            // drains stageA + ds_writes
  }

  const int row0 = b0 + wm * 64 + (lane >> 4) * 4;
  const int col0 = n0 + wn * 64 + (lane & 15);
  if constexpr (USE_ATOMIC) {
    #pragma unroll
    for (int i = 0; i < 4; ++i)
      #pragma unroll
      for (int j = 0; j < 4; ++j)
        #pragma unroll
        for (int r = 0; r < 4; ++r)
          atomicAdd(&dst[(size_t)(row0 + i * 16 + r) * H_ + col0 + j * 16], acc[i][j][r]);
  } else {
    float* P = dst + (size_t)sk * (B_ * H_);
    #pragma unroll
    for (int i = 0; i < 4; ++i)
      #pragma unroll
      for (int j = 0; j < 4; ++j)
        #pragma unroll
        for (int r = 0; r < 4; ++r)
          P[(size_t)(row0 + i * 16 + r) * H_ + col0 + j * 16] = acc[i][j][r];
  }
}

// ---------------- kernel 3: fused reduce + relu + GEMM2 ----------------
// out[b][v] = b2[v] + sum_n relu(b1[n] + sum_sk P[sk][b][n]) * W2[n][v]
template<bool FROM_PARTIALS>
__global__ __launch_bounds__(256) void gemm2_kernel(
    const float* __restrict__ Pin, const float* __restrict__ b1,
    const float* __restrict__ W2, const float* __restrict__ b2,
    float* __restrict__ out)
{
  const int bb = blockIdx.x * 2;   // 256 blocks, 2 batch rows each
  const int v  = threadIdx.x;      // 0..255
  __shared__ float hs[2][H_];

  // build hs = relu(b1 + sum P) : each thread owns 4 h-elements (f32x4)
  {
    const int id  = v * 4;                 // 0..1020 over 2*512
    const int row = id >> 9, col = id & 511;
    f32x4 s;
    if constexpr (FROM_PARTIALS) {
      s = *(const f32x4*)(b1 + col);
      #pragma unroll 4
      for (int sk = 0; sk < SPLITK; ++sk)
        s += *(const f32x4*)(Pin + (size_t)sk * (B_ * H_) + (size_t)(bb + row) * H_ + col);
    } else {
      s = *(const f32x4*)(Pin + (size_t)(bb + row) * H_ + col);  // h_pre already has b1
    }
    f32x4 r;
    #pragma unroll
    for (int t = 0; t < 4; ++t) r[t] = fmaxf(s[t], 0.f);
    *(f32x4*)&hs[row][col] = r;
  }
  __syncthreads();

  float a0 = 0.f, a1 = 0.f;
  for (int j4 = 0; j4 < H_ / 4; ++j4) {
    f32x4 h0 = *(const f32x4*)&hs[0][j4 * 4];
    f32x4 h1 = *(const f32x4*)&hs[1][j4 * 4];
    #pragma unroll
    for (int t = 0; t < 4; ++t) {
      float w = W2[(size_t)(j4 * 4 + t) * V_ + v];
      a0 += h0[t] * w; a1 += h1[t] * w;
    }
  }
  const float bias = b2[v];
  out[(size_t)(bb + 0) * V_ + v] = a0 + bias;
  out[(size_t)(bb + 1) * V_ + v] = a1 + bias;
}

// ---------------- launch ----------------
extern "C" void kernel_launch(void* const* d_in, const int* in_sizes, int n_in,
                              void* d_out, int out_size, void* d_ws, size_t ws_size,
                              hipStream_t stream) {
  const float* x   = (const float*)d_in[0];
  const float* mem = (const float*)d_in[1];
  const int*   tim = (const int*)d_in[2];
  const float* msu = (const float*)d_in[3];
  const float* W1  = (const float*)d_in[5];
  const float* b1  = (const float*)d_in[6];
  const float* W2  = (const float*)d_in[7];
  const float* b2  = (const float*)d_in[8];
  float* out = (float*)d_out;

  char* ws = (char*)d_ws;
  const size_t abytes = (size_t)B_ * KTOT * 2;          // 35,651,584
  const size_t pbytes = (size_t)SPLITK * B_ * H_ * 4;   // 33,554,432
  const size_t hbytes = (size_t)B_ * H_ * 4;            // 1,048,576
  const bool partials = ws_size >= abytes + pbytes + hbytes;

  ushort* A_ws  = (ushort*)ws;
  float*  P     = (float*)(ws + abytes);
  float*  h_pre = partials ? (float*)(ws + abytes + pbytes)
                           : (float*)(ws + abytes);

  prep_kernel<<<B_, 256, 0, stream>>>(x, mem, tim, msu, b1, A_ws, h_pre);
  if (partials) {
    gemm1_kernel<false><<<8 * SPLITK, 512, 0, stream>>>(A_ws, W1, P);
    gemm2_kernel<true><<<B_ / 2, 256, 0, stream>>>(P, b1, W2, b2, out);
  } else {
    gemm1_kernel<true><<<8 * SPLITK, 512, 0, stream>>>(A_ws, W1, h_pre);
    gemm2_kernel<false><<<B_ / 2, 256, 0, stream>>>(h_pre, b1, W2, b2, out);
  }
}